// Round 14
// baseline (152.560 us; speedup 1.0000x reference)
//
#include <hip/hip_runtime.h>
#include <hip/hip_bf16.h>
#include <math.h>

#define S 4096
#define D 512
#define H 8
#define DK 64
#define WIN 128

typedef __attribute__((ext_vector_type(8))) short bf16x8;
typedef __attribute__((ext_vector_type(4))) float f32x4;

__device__ __forceinline__ unsigned short f2bf(float f) {
    __hip_bfloat16 h = __float2bfloat16(f);
    return *(unsigned short*)&h;
}

// ---------------------------------------------------------------------------
// fp32 -> bf16: x (y=0) and the 4 weight matrices (y=1..4). 8 elems/thread.
// ---------------------------------------------------------------------------
__global__ __launch_bounds__(256) void conv_bf16_kernel(
    const float* __restrict__ x,
    const float* __restrict__ wq, const float* __restrict__ wk,
    const float* __restrict__ wv, const float* __restrict__ wo,
    unsigned short* __restrict__ xb,
    unsigned short* __restrict__ wqb, unsigned short* __restrict__ wkb,
    unsigned short* __restrict__ wvb, unsigned short* __restrict__ wob)
{
    const float* src; unsigned short* dst; int n;
    switch (blockIdx.y) {
        case 0:  src = x;  dst = xb;  n = S * D; break;
        case 1:  src = wq; dst = wqb; n = D * D; break;
        case 2:  src = wk; dst = wkb; n = D * D; break;
        case 3:  src = wv; dst = wvb; n = D * D; break;
        default: src = wo; dst = wob; n = D * D; break;
    }
    const int i = (blockIdx.x * 256 + threadIdx.x) * 8;
    if (i >= n) return;
    float4 a = *(const float4*)&src[i];
    float4 b = *(const float4*)&src[i + 4];
    ushort4 o0 = {f2bf(a.x), f2bf(a.y), f2bf(a.z), f2bf(a.w)};
    ushort4 o1 = {f2bf(b.x), f2bf(b.y), f2bf(b.z), f2bf(b.w)};
    *(ushort4*)&dst[i]     = o0;
    *(ushort4*)&dst[i + 4] = o1;
}

// ---------------------------------------------------------------------------
// V transpose: vb (S x 512, bf16, head-major cols) -> vT[512][4096]
// vT[(h*64+d)*4096 + s] = V[s][h*64+d]. LDS-tiled 64x64. Grid (64, 8).
// ---------------------------------------------------------------------------
__global__ __launch_bounds__(256) void vtrans_kernel(
    const unsigned short* __restrict__ vb, unsigned short* __restrict__ vT)
{
    __shared__ unsigned short T[64][72];
    const int tid = threadIdx.x;
    const int s0 = blockIdx.x * 64;
    const int h  = blockIdx.y;
    const int r = tid >> 2;            // s-offset 0..63
    const int c = (tid & 3) * 16;      // d-offset {0,16,32,48}
    *(bf16x8*)&T[r][c]     = *(const bf16x8*)&vb[(size_t)(s0 + r) * 512 + h * 64 + c];
    *(bf16x8*)&T[r][c + 8] = *(const bf16x8*)&vb[(size_t)(s0 + r) * 512 + h * 64 + c + 8];
    __syncthreads();
    unsigned short o[16];
    #pragma unroll
    for (int e = 0; e < 16; ++e) o[e] = T[c + e][r];   // d-row r, s = c+e
    unsigned short* dst = &vT[((size_t)h * 64 + r) * 4096 + s0 + c];
    *(bf16x8*)&dst[0] = *(bf16x8*)&o[0];
    *(bf16x8*)&dst[8] = *(bf16x8*)&o[8];
}

// ---------------------------------------------------------------------------
// MFMA GEMM: C[m][n] = sum_e A[m][e]*W16[n][e] + bias[n]
// A, W16 bf16. B-tile (64 rows x 512 K) staged bf16 -> padded LDS.
// ---------------------------------------------------------------------------
__device__ __forceinline__ void mfma_gemm_body(
    const unsigned short* __restrict__ A,
    const unsigned short* __restrict__ W16,
    const float* __restrict__ bias,
    float* __restrict__ C,
    unsigned short* __restrict__ CB)
{
    __shared__ unsigned short Bs[64][520];

    const int tid  = threadIdx.x;
    const int m0   = blockIdx.x * 128;
    const int n0   = blockIdx.y * 64;
    const int wv   = tid >> 6;
    const int lane = tid & 63;
    const int l16  = lane & 15;
    const int klo  = (lane >> 4) * 8;

    #pragma unroll
    for (int it = 0; it < 16; ++it) {
        const int c   = tid + it * 256;
        const int row = c >> 6;
        const int kc  = (c & 63) * 8;
        *(bf16x8*)&Bs[row][kc] =
            *(const bf16x8*)&W16[(size_t)(n0 + row) * 512 + kc];
    }
    __syncthreads();

    const unsigned short* arow0 = &A[(size_t)(m0 + wv * 32 + l16) * 512 + klo];
    const unsigned short* arow1 = arow0 + 16 * 512;

    f32x4 acc[2][4];
    #pragma unroll
    for (int r = 0; r < 2; ++r)
        #pragma unroll
        for (int nf = 0; nf < 4; ++nf)
            acc[r][nf] = (f32x4){0.f, 0.f, 0.f, 0.f};

    #pragma unroll 4
    for (int kb = 0; kb < 512; kb += 32) {
        bf16x8 a0 = *(const bf16x8*)&arow0[kb];
        bf16x8 a1 = *(const bf16x8*)&arow1[kb];
        #pragma unroll
        for (int nf = 0; nf < 4; ++nf) {
            bf16x8 b = *(const bf16x8*)&Bs[nf * 16 + l16][kb + klo];
            acc[0][nf] = __builtin_amdgcn_mfma_f32_16x16x32_bf16(a0, b, acc[0][nf], 0, 0, 0);
            acc[1][nf] = __builtin_amdgcn_mfma_f32_16x16x32_bf16(a1, b, acc[1][nf], 0, 0, 0);
        }
    }

    const int r0 = (lane >> 4) * 4;
    #pragma unroll
    for (int r = 0; r < 2; ++r) {
        #pragma unroll
        for (int nf = 0; nf < 4; ++nf) {
            const int col = n0 + nf * 16 + l16;
            const float bb = bias[col];
            #pragma unroll
            for (int vv = 0; vv < 4; ++vv) {
                const int row = m0 + wv * 32 + r * 16 + r0 + vv;
                const float val = acc[r][nf][vv] + bb;
                if (C)  C [(size_t)row * 512 + col] = val;
                if (CB) CB[(size_t)row * 512 + col] = f2bf(val);
            }
        }
    }
}

__global__ __launch_bounds__(256) void proj3_kernel(
    const unsigned short* __restrict__ xb,
    const unsigned short* __restrict__ wqb, const float* __restrict__ bq,
    const unsigned short* __restrict__ wkb, const float* __restrict__ bk,
    const unsigned short* __restrict__ wvb, const float* __restrict__ bv,
    unsigned short* __restrict__ qb, unsigned short* __restrict__ kb,
    unsigned short* __restrict__ vb)
{
    const unsigned short* W; const float* b; unsigned short* CB;
    if (blockIdx.z == 0)      { W = wqb; b = bq; CB = qb; }
    else if (blockIdx.z == 1) { W = wkb; b = bk; CB = kb; }
    else                      { W = wvb; b = bv; CB = vb; }
    mfma_gemm_body(xb, W, b, nullptr, CB);
}

__global__ __launch_bounds__(256) void outproj_kernel(
    const unsigned short* __restrict__ ctxb,
    const unsigned short* __restrict__ wob, const float* __restrict__ bo,
    float* __restrict__ out)
{
    mfma_gemm_body(ctxb, wob, bo, out, nullptr);
}

// ---------------------------------------------------------------------------
// Fused band attention, fragment-direct (no K/V staging, no Q LDS):
// MFMA QK^T (A,B frags straight from global qb/kb) -> softmax (P zeroed
// out-of-band) -> MFMA PV (B frags from pre-transposed vT) -> ctx ->
// full-row attn write. LDS = P only (~22 KB) -> ~7 blocks/CU; 2 barriers.
// QB=16, grid (256, 8). Clamped reads are safe: P=0 wherever clamp applies.
// ---------------------------------------------------------------------------
__global__ __launch_bounds__(256) void band_attn_kernel(
    const unsigned short* __restrict__ qb, const unsigned short* __restrict__ kb,
    const unsigned short* __restrict__ vT,
    float* __restrict__ attn, unsigned short* __restrict__ ctxb)
{
    __shared__ float P[16][340];     // exp-scores, stride 340 (bank-spread, 16B-aligned)
    __shared__ float rinvs[16];

    const int tid = threadIdx.x;
    const int h  = blockIdx.y;
    const int q0 = blockIdx.x * 16;
    const int w0 = q0 - 128;

    const int wv   = tid >> 6;
    const int lane = tid & 63;
    const int l16  = lane & 15;
    const int klo  = (lane >> 4) * 8;
    const int r0   = (lane >> 4) * 4;

    // Q fragments (chunk-invariant) straight from global
    const unsigned short* qrow = &qb[(size_t)(q0 + l16) * 512 + h * 64 + klo];
    const bf16x8 aq0 = *(const bf16x8*)&qrow[0];
    const bf16x8 aq1 = *(const bf16x8*)&qrow[32];

    // ================= QK^T: B-fragments straight from kb =================
    for (int ch = 0; ch < 5; ++ch) {
        const int c0 = w0 + ch * 64;
        if (c0 + 64 <= 0 || c0 >= S) continue;          // fully-outside chunks
        const int krow = min(max(c0 + wv * 16 + l16, 0), S - 1);  // clamp partials
        const unsigned short* krp = &kb[(size_t)krow * 512 + h * 64 + klo];
        bf16x8 b0 = *(const bf16x8*)&krp[0];
        bf16x8 b1 = *(const bf16x8*)&krp[32];
        f32x4 acc = (f32x4){0.f, 0.f, 0.f, 0.f};
        acc = __builtin_amdgcn_mfma_f32_16x16x32_bf16(aq0, b0, acc, 0, 0, 0);
        acc = __builtin_amdgcn_mfma_f32_16x16x32_bf16(aq1, b1, acc, 0, 0, 0);
        #pragma unroll
        for (int vv = 0; vv < 4; ++vv)
            P[r0 + vv][ch * 64 + wv * 16 + l16] = acc[vv] * 0.125f;
    }
    __syncthreads();                                    // barrier 1

    // ---- softmax: exp in band, ZERO outside band (cols [0,320)) ----
    {
        const int r   = tid >> 4;
        const int lx  = tid & 15;
        const int i   = q0 + r;
        const int lo = max(i - WIN, 0) - w0;
        const int hi = min(i + WIN, S - 1) - w0;

        float m = -1e30f;
        for (int c = lo + lx; c <= hi; c += 16) m = fmaxf(m, P[r][c]);
        m = fmaxf(m, __shfl_xor(m, 1));
        m = fmaxf(m, __shfl_xor(m, 2));
        m = fmaxf(m, __shfl_xor(m, 4));
        m = fmaxf(m, __shfl_xor(m, 8));

        float sum = 0.f;
        for (int c = lx; c < 320; c += 16) {
            float e = 0.f;
            if (c >= lo && c <= hi) {
                e = __expf(P[r][c] - m);
                sum += e;
            }
            P[r][c] = e;
        }
        sum += __shfl_xor(sum, 1);
        sum += __shfl_xor(sum, 2);
        sum += __shfl_xor(sum, 4);
        sum += __shfl_xor(sum, 8);
        if (lx == 0) rinvs[r] = 1.0f / sum;
    }
    __syncthreads();                                    // barrier 2 (last)

    // ================= PV: B-fragments straight from vT =================
    f32x4 pacc = (f32x4){0.f, 0.f, 0.f, 0.f};
    const unsigned short* vtrow = &vT[((size_t)h * 64 + wv * 16 + l16) * 4096];
    for (int ch = 0; ch < 5; ++ch) {
        const int c0 = w0 + ch * 64;
        if (c0 + 64 <= 0 || c0 >= S) continue;
        #pragma unroll
        for (int kk = 0; kk < 64; kk += 32) {
            f32x4 p0 = *(const f32x4*)&P[l16][ch * 64 + kk + klo];
            f32x4 p1 = *(const f32x4*)&P[l16][ch * 64 + kk + klo + 4];
            unsigned short ab[8] = {f2bf(p0[0]), f2bf(p0[1]), f2bf(p0[2]), f2bf(p0[3]),
                                    f2bf(p1[0]), f2bf(p1[1]), f2bf(p1[2]), f2bf(p1[3])};
            bf16x8 a = *(const bf16x8*)ab;
            int offs = c0 + kk + klo;                   // multiple of 8
            offs = min(max(offs, 0), S - 8);            // clamp: P=0 there
            bf16x8 b = *(const bf16x8*)&vtrow[offs];
            pacc = __builtin_amdgcn_mfma_f32_16x16x32_bf16(a, b, pacc, 0, 0, 0);
        }
    }

    // ---- ctx write ----
    #pragma unroll
    for (int vv = 0; vv < 4; ++vv) {
        const int row = q0 + r0 + vv;
        ctxb[(size_t)row * 512 + h * 64 + wv * 16 + l16] =
            f2bf(pacc[vv] * rinvs[r0 + vv]);
    }

    // ---- write full attn rows, coalesced; zeros outside band ----
    float* rowbase = attn + (size_t)h * S * S;
    #pragma unroll 1
    for (int r = 0; r < 16; ++r) {
        const int i = q0 + r;
        float* rowp = rowbase + (size_t)i * S;
        const int lo = max(i - WIN, 0) - w0;
        const int hi = min(i + WIN, S - 1) - w0;
        const float rv = rinvs[r];
        #pragma unroll
        for (int t = 0; t < 4; ++t) {
            const int c4 = (tid + t * 256) << 2;
            const int lc = c4 - w0;
            float4 o;
            if (lc >= lo && lc + 3 <= hi) {
                float4 p = *(const float4*)&P[r][lc];
                o.x = p.x * rv; o.y = p.y * rv; o.z = p.z * rv; o.w = p.w * rv;
            } else if (lc + 3 < lo || lc > hi) {
                o = make_float4(0.f, 0.f, 0.f, 0.f);
            } else {
                o.x = (lc + 0 >= lo && lc + 0 <= hi) ? P[r][lc + 0] * rv : 0.f;
                o.y = (lc + 1 >= lo && lc + 1 <= hi) ? P[r][lc + 1] * rv : 0.f;
                o.z = (lc + 2 >= lo && lc + 2 <= hi) ? P[r][lc + 2] * rv : 0.f;
                o.w = (lc + 3 >= lo && lc + 3 <= hi) ? P[r][lc + 3] * rv : 0.f;
            }
            *(float4*)&rowp[c4] = o;
        }
    }
}

// ---------------------------------------------------------------------------
extern "C" void kernel_launch(void* const* d_in, const int* in_sizes, int n_in,
                              void* d_out, int out_size, void* d_ws, size_t ws_size,
                              hipStream_t stream)
{
    (void)in_sizes; (void)n_in; (void)out_size; (void)ws_size;
    const float* x  = (const float*)d_in[0];
    const float* wq = (const float*)d_in[1];
    const float* bq = (const float*)d_in[2];
    const float* wk = (const float*)d_in[3];
    const float* bk = (const float*)d_in[4];
    const float* wv = (const float*)d_in[5];
    const float* bv = (const float*)d_in[6];
    const float* wo = (const float*)d_in[7];
    const float* bo = (const float*)d_in[8];

    float* out  = (float*)d_out;                       // (S, D)
    float* attn = out + (size_t)S * D;                 // (H, S, S)

    unsigned short* xb   = (unsigned short*)d_ws;      // 4 MB each
    unsigned short* qb   = xb   + (size_t)S * D;
    unsigned short* kb   = qb   + (size_t)S * D;
    unsigned short* vb   = kb   + (size_t)S * D;
    unsigned short* ctxb = vb   + (size_t)S * D;
    unsigned short* vT   = ctxb + (size_t)S * D;       // 4 MB (512 x 4096)
    unsigned short* wqb  = vT   + (size_t)S * D;       // 512 KB each
    unsigned short* wkb  = wqb  + (size_t)D * D;
    unsigned short* wvb  = wkb  + (size_t)D * D;
    unsigned short* wob  = wvb  + (size_t)D * D;

    conv_bf16_kernel<<<dim3(1024, 5), 256, 0, stream>>>(
        x, wq, wk, wv, wo, xb, wqb, wkb, wvb, wob);
    proj3_kernel<<<dim3(32, 8, 3), 256, 0, stream>>>(
        xb, wqb, bq, wkb, bk, wvb, bv, qb, kb, vb);
    vtrans_kernel<<<dim3(64, 8), 256, 0, stream>>>(vb, vT);
    band_attn_kernel<<<dim3(256, 8), 256, 0, stream>>>(qb, kb, vT, attn, ctxb);
    outproj_kernel<<<dim3(32, 8), 256, 0, stream>>>(ctxb, wob, bo, out);
}

// Round 15
// 148.332 us; speedup vs baseline: 1.0285x; 1.0285x over previous
//
#include <hip/hip_runtime.h>
#include <hip/hip_bf16.h>
#include <math.h>

#define S 4096
#define D 512
#define H 8
#define DK 64
#define WIN 128

typedef __attribute__((ext_vector_type(8))) short bf16x8;
typedef __attribute__((ext_vector_type(4))) float f32x4;

__device__ __forceinline__ unsigned short f2bf(float f) {
    __hip_bfloat16 h = __float2bfloat16(f);
    return *(unsigned short*)&h;
}

// ---------------------------------------------------------------------------
// fp32 -> bf16: x (y=0) and the 4 weight matrices (y=1..4). 8 elems/thread.
// ---------------------------------------------------------------------------
__global__ __launch_bounds__(256) void conv_bf16_kernel(
    const float* __restrict__ x,
    const float* __restrict__ wq, const float* __restrict__ wk,
    const float* __restrict__ wv, const float* __restrict__ wo,
    unsigned short* __restrict__ xb,
    unsigned short* __restrict__ wqb, unsigned short* __restrict__ wkb,
    unsigned short* __restrict__ wvb, unsigned short* __restrict__ wob)
{
    const float* src; unsigned short* dst; int n;
    switch (blockIdx.y) {
        case 0:  src = x;  dst = xb;  n = S * D; break;
        case 1:  src = wq; dst = wqb; n = D * D; break;
        case 2:  src = wk; dst = wkb; n = D * D; break;
        case 3:  src = wv; dst = wvb; n = D * D; break;
        default: src = wo; dst = wob; n = D * D; break;
    }
    const int i = (blockIdx.x * 256 + threadIdx.x) * 8;
    if (i >= n) return;
    float4 a = *(const float4*)&src[i];
    float4 b = *(const float4*)&src[i + 4];
    ushort4 o0 = {f2bf(a.x), f2bf(a.y), f2bf(a.z), f2bf(a.w)};
    ushort4 o1 = {f2bf(b.x), f2bf(b.y), f2bf(b.z), f2bf(b.w)};
    *(ushort4*)&dst[i]     = o0;
    *(ushort4*)&dst[i + 4] = o1;
}

// ---------------------------------------------------------------------------
// V transpose: vb (S x 512, head-major cols) -> vT[(h*64+d)*4096 + s].
// LDS-tiled 64x64. Grid (64, 8). (Verified in round 14.)
// ---------------------------------------------------------------------------
__global__ __launch_bounds__(256) void vtrans_kernel(
    const unsigned short* __restrict__ vb, unsigned short* __restrict__ vT)
{
    __shared__ unsigned short T[64][72];
    const int tid = threadIdx.x;
    const int s0 = blockIdx.x * 64;
    const int h  = blockIdx.y;
    const int r = tid >> 2;            // s-offset 0..63
    const int c = (tid & 3) * 16;      // d-offset {0,16,32,48}
    *(bf16x8*)&T[r][c]     = *(const bf16x8*)&vb[(size_t)(s0 + r) * 512 + h * 64 + c];
    *(bf16x8*)&T[r][c + 8] = *(const bf16x8*)&vb[(size_t)(s0 + r) * 512 + h * 64 + c + 8];
    __syncthreads();
    unsigned short o[16];
    #pragma unroll
    for (int e = 0; e < 16; ++e) o[e] = T[c + e][r];   // d-row r, s = c+e
    unsigned short* dst = &vT[((size_t)h * 64 + r) * 4096 + s0 + c];
    *(bf16x8*)&dst[0] = *(bf16x8*)&o[0];
    *(bf16x8*)&dst[8] = *(bf16x8*)&o[8];
}

// ---------------------------------------------------------------------------
// MFMA GEMM: C[m][n] = sum_e A[m][e]*W16[n][e] + bias[n]
// A, W16 bf16. B-tile (64 rows x 512 K) staged bf16 -> padded LDS.
// ---------------------------------------------------------------------------
__device__ __forceinline__ void mfma_gemm_body(
    const unsigned short* __restrict__ A,
    const unsigned short* __restrict__ W16,
    const float* __restrict__ bias,
    float* __restrict__ C,
    unsigned short* __restrict__ CB)
{
    __shared__ unsigned short Bs[64][520];

    const int tid  = threadIdx.x;
    const int m0   = blockIdx.x * 128;
    const int n0   = blockIdx.y * 64;
    const int wv   = tid >> 6;
    const int lane = tid & 63;
    const int l16  = lane & 15;
    const int klo  = (lane >> 4) * 8;

    #pragma unroll
    for (int it = 0; it < 16; ++it) {
        const int c   = tid + it * 256;
        const int row = c >> 6;
        const int kc  = (c & 63) * 8;
        *(bf16x8*)&Bs[row][kc] =
            *(const bf16x8*)&W16[(size_t)(n0 + row) * 512 + kc];
    }
    __syncthreads();

    const unsigned short* arow0 = &A[(size_t)(m0 + wv * 32 + l16) * 512 + klo];
    const unsigned short* arow1 = arow0 + 16 * 512;

    f32x4 acc[2][4];
    #pragma unroll
    for (int r = 0; r < 2; ++r)
        #pragma unroll
        for (int nf = 0; nf < 4; ++nf)
            acc[r][nf] = (f32x4){0.f, 0.f, 0.f, 0.f};

    #pragma unroll 4
    for (int kb = 0; kb < 512; kb += 32) {
        bf16x8 a0 = *(const bf16x8*)&arow0[kb];
        bf16x8 a1 = *(const bf16x8*)&arow1[kb];
        #pragma unroll
        for (int nf = 0; nf < 4; ++nf) {
            bf16x8 b = *(const bf16x8*)&Bs[nf * 16 + l16][kb + klo];
            acc[0][nf] = __builtin_amdgcn_mfma_f32_16x16x32_bf16(a0, b, acc[0][nf], 0, 0, 0);
            acc[1][nf] = __builtin_amdgcn_mfma_f32_16x16x32_bf16(a1, b, acc[1][nf], 0, 0, 0);
        }
    }

    const int r0 = (lane >> 4) * 4;
    #pragma unroll
    for (int r = 0; r < 2; ++r) {
        #pragma unroll
        for (int nf = 0; nf < 4; ++nf) {
            const int col = n0 + nf * 16 + l16;
            const float bb = bias[col];
            #pragma unroll
            for (int vv = 0; vv < 4; ++vv) {
                const int row = m0 + wv * 32 + r * 16 + r0 + vv;
                const float val = acc[r][nf][vv] + bb;
                if (C)  C [(size_t)row * 512 + col] = val;
                if (CB) CB[(size_t)row * 512 + col] = f2bf(val);
            }
        }
    }
}

__global__ __launch_bounds__(256) void proj3_kernel(
    const unsigned short* __restrict__ xb,
    const unsigned short* __restrict__ wqb, const float* __restrict__ bq,
    const unsigned short* __restrict__ wkb, const float* __restrict__ bk,
    const unsigned short* __restrict__ wvb, const float* __restrict__ bv,
    unsigned short* __restrict__ qb, unsigned short* __restrict__ kb,
    unsigned short* __restrict__ vb)
{
    const unsigned short* W; const float* b; unsigned short* CB;
    if (blockIdx.z == 0)      { W = wqb; b = bq; CB = qb; }
    else if (blockIdx.z == 1) { W = wkb; b = bk; CB = kb; }
    else                      { W = wvb; b = bv; CB = vb; }
    mfma_gemm_body(xb, W, b, nullptr, CB);
}

__global__ __launch_bounds__(256) void outproj_kernel(
    const unsigned short* __restrict__ ctxb,
    const unsigned short* __restrict__ wob, const float* __restrict__ bo,
    float* __restrict__ out)
{
    mfma_gemm_body(ctxb, wob, bo, out, nullptr);
}

// ---------------------------------------------------------------------------
// Fused band attention (r13 structure + register-Q + vector V staging):
// MFMA QK^T (K staged to LDS) -> softmax (P zeroed out-of-band) -> MFMA PV
// (V chunk staged from pre-transposed vT via VECTOR LDS writes into the same
// KV buffer, layout [d][s_local]) -> ctx write -> full-row attn write.
// LDS ~31 KB -> 5 blocks/CU. QB=16, grid (256, 8).
// ---------------------------------------------------------------------------
__global__ __launch_bounds__(256) void band_attn_kernel(
    const unsigned short* __restrict__ qb, const unsigned short* __restrict__ kb,
    const unsigned short* __restrict__ vT,
    float* __restrict__ attn, unsigned short* __restrict__ ctxb)
{
    __shared__ __align__(16) unsigned short KV[64][72];  // K:[key][d] / V:[d][s]
    __shared__ float P[16][336];                         // exp-scores
    __shared__ float rinvs[16];

    const int tid = threadIdx.x;
    const int h  = blockIdx.y;
    const int q0 = blockIdx.x * 16;
    const int w0 = q0 - 128;

    const int wv   = tid >> 6;
    const int lane = tid & 63;
    const int l16  = lane & 15;
    const int klo  = (lane >> 4) * 8;
    const int r0   = (lane >> 4) * 4;

    // ---- Q fragments in registers (chunk-invariant), straight from global
    const unsigned short* qrow = &qb[(size_t)(q0 + l16) * 512 + h * 64 + klo];
    const bf16x8 aq0 = *(const bf16x8*)&qrow[0];
    const bf16x8 aq1 = *(const bf16x8*)&qrow[32];

    const int lr = tid >> 2;           // K stage: key 0..63
    const int ld = (tid & 3) * 16;     // K stage: 16 d's

    // ================= QK^T phase =================
    for (int ch = 0; ch < 5; ++ch) {
        const int c0 = w0 + ch * 64;
        if (c0 + 64 <= 0 || c0 >= S) continue;   // skip fully-outside chunks
        __syncthreads();
        {
            const int krow = min(max(c0 + lr, 0), S - 1);   // clamp partials
            const unsigned short* src = &kb[(size_t)krow * 512 + h * 64 + ld];
            *(bf16x8*)&KV[lr][ld]     = *(const bf16x8*)&src[0];
            *(bf16x8*)&KV[lr][ld + 8] = *(const bf16x8*)&src[8];
        }
        __syncthreads();

        f32x4 acc = (f32x4){0.f, 0.f, 0.f, 0.f};
        bf16x8 b0 = *(const bf16x8*)&KV[wv * 16 + l16][klo];
        bf16x8 b1 = *(const bf16x8*)&KV[wv * 16 + l16][32 + klo];
        acc = __builtin_amdgcn_mfma_f32_16x16x32_bf16(aq0, b0, acc, 0, 0, 0);
        acc = __builtin_amdgcn_mfma_f32_16x16x32_bf16(aq1, b1, acc, 0, 0, 0);
        #pragma unroll
        for (int vv = 0; vv < 4; ++vv)
            P[r0 + vv][ch * 64 + wv * 16 + l16] = acc[vv] * 0.125f;
    }
    __syncthreads();

    // ---- softmax: exp in band, ZERO outside band (cols [0,320)) ----
    {
        const int r   = tid >> 4;
        const int lx  = tid & 15;
        const int i   = q0 + r;
        const int lo = max(i - WIN, 0) - w0;
        const int hi = min(i + WIN, S - 1) - w0;

        float m = -1e30f;
        for (int c = lo + lx; c <= hi; c += 16) m = fmaxf(m, P[r][c]);
        m = fmaxf(m, __shfl_xor(m, 1));
        m = fmaxf(m, __shfl_xor(m, 2));
        m = fmaxf(m, __shfl_xor(m, 4));
        m = fmaxf(m, __shfl_xor(m, 8));

        float sum = 0.f;
        for (int c = lx; c < 320; c += 16) {
            float e = 0.f;
            if (c >= lo && c <= hi) {
                e = __expf(P[r][c] - m);
                sum += e;
            }
            P[r][c] = e;
        }
        sum += __shfl_xor(sum, 1);
        sum += __shfl_xor(sum, 2);
        sum += __shfl_xor(sum, 4);
        sum += __shfl_xor(sum, 8);
        if (lx == 0) rinvs[r] = 1.0f / sum;
    }

    // ================= PV phase: V staged from vT (vector LDS writes) ======
    f32x4 pacc = (f32x4){0.f, 0.f, 0.f, 0.f};
    const int dd = tid >> 2;           // V stage: d 0..63
    const int sc = (tid & 3) * 16;     // V stage: 16 s's
    const unsigned short* vtd = &vT[((size_t)h * 64 + dd) * 4096];
    for (int ch = 0; ch < 5; ++ch) {
        const int c0 = w0 + ch * 64;
        if (c0 + 64 <= 0 || c0 >= S) continue;
        __syncthreads();
        {
            const int offs = min(max(c0 + sc, 0), S - 16);  // 16-aligned clamp; P=0 there
            *(bf16x8*)&KV[dd][sc]     = *(const bf16x8*)&vtd[offs];
            *(bf16x8*)&KV[dd][sc + 8] = *(const bf16x8*)&vtd[offs + 8];
        }
        __syncthreads();

        #pragma unroll
        for (int kk = 0; kk < 64; kk += 32) {
            f32x4 p0 = *(const f32x4*)&P[l16][ch * 64 + kk + klo];
            f32x4 p1 = *(const f32x4*)&P[l16][ch * 64 + kk + klo + 4];
            unsigned short ab[8] = {f2bf(p0[0]), f2bf(p0[1]), f2bf(p0[2]), f2bf(p0[3]),
                                    f2bf(p1[0]), f2bf(p1[1]), f2bf(p1[2]), f2bf(p1[3])};
            bf16x8 a = *(const bf16x8*)ab;
            bf16x8 b = *(const bf16x8*)&KV[wv * 16 + l16][kk + klo];
            pacc = __builtin_amdgcn_mfma_f32_16x16x32_bf16(a, b, pacc, 0, 0, 0);
        }
    }

    // ---- ctx write ----
    #pragma unroll
    for (int vv = 0; vv < 4; ++vv) {
        const int row = q0 + r0 + vv;
        ctxb[(size_t)row * 512 + h * 64 + wv * 16 + l16] =
            f2bf(pacc[vv] * rinvs[r0 + vv]);
    }

    // ---- write full attn rows, coalesced; zeros outside band ----
    float* rowbase = attn + (size_t)h * S * S;
    #pragma unroll 1
    for (int r = 0; r < 16; ++r) {
        const int i = q0 + r;
        float* rowp = rowbase + (size_t)i * S;
        const int lo = max(i - WIN, 0) - w0;
        const int hi = min(i + WIN, S - 1) - w0;
        const float rv = rinvs[r];
        #pragma unroll
        for (int t = 0; t < 4; ++t) {
            const int c4 = (tid + t * 256) << 2;
            const int lc = c4 - w0;
            float4 o;
            if (lc >= lo && lc + 3 <= hi) {
                float4 p = *(const float4*)&P[r][lc];
                o.x = p.x * rv; o.y = p.y * rv; o.z = p.z * rv; o.w = p.w * rv;
            } else if (lc + 3 < lo || lc > hi) {
                o = make_float4(0.f, 0.f, 0.f, 0.f);
            } else {
                o.x = (lc + 0 >= lo && lc + 0 <= hi) ? P[r][lc + 0] * rv : 0.f;
                o.y = (lc + 1 >= lo && lc + 1 <= hi) ? P[r][lc + 1] * rv : 0.f;
                o.z = (lc + 2 >= lo && lc + 2 <= hi) ? P[r][lc + 2] * rv : 0.f;
                o.w = (lc + 3 >= lo && lc + 3 <= hi) ? P[r][lc + 3] * rv : 0.f;
            }
            *(float4*)&rowp[c4] = o;
        }
    }
}

// ---------------------------------------------------------------------------
extern "C" void kernel_launch(void* const* d_in, const int* in_sizes, int n_in,
                              void* d_out, int out_size, void* d_ws, size_t ws_size,
                              hipStream_t stream)
{
    (void)in_sizes; (void)n_in; (void)out_size; (void)ws_size;
    const float* x  = (const float*)d_in[0];
    const float* wq = (const float*)d_in[1];
    const float* bq = (const float*)d_in[2];
    const float* wk = (const float*)d_in[3];
    const float* bk = (const float*)d_in[4];
    const float* wv = (const float*)d_in[5];
    const float* bv = (const float*)d_in[6];
    const float* wo = (const float*)d_in[7];
    const float* bo = (const float*)d_in[8];

    float* out  = (float*)d_out;                       // (S, D)
    float* attn = out + (size_t)S * D;                 // (H, S, S)

    unsigned short* xb   = (unsigned short*)d_ws;      // 4 MB each
    unsigned short* qb   = xb   + (size_t)S * D;
    unsigned short* kb   = qb   + (size_t)S * D;
    unsigned short* vb   = kb   + (size_t)S * D;
    unsigned short* ctxb = vb   + (size_t)S * D;
    unsigned short* vT   = ctxb + (size_t)S * D;       // 4 MB (512 x 4096)
    unsigned short* wqb  = vT   + (size_t)S * D;       // 512 KB each
    unsigned short* wkb  = wqb  + (size_t)D * D;
    unsigned short* wvb  = wkb  + (size_t)D * D;
    unsigned short* wob  = wvb  + (size_t)D * D;

    conv_bf16_kernel<<<dim3(1024, 5), 256, 0, stream>>>(
        x, wq, wk, wv, wo, xb, wqb, wkb, wvb, wob);
    proj3_kernel<<<dim3(32, 8, 3), 256, 0, stream>>>(
        xb, wqb, bq, wkb, bk, wvb, bv, qb, kb, vb);
    vtrans_kernel<<<dim3(64, 8), 256, 0, stream>>>(vb, vT);
    band_attn_kernel<<<dim3(256, 8), 256, 0, stream>>>(qb, kb, vT, attn, ctxb);
    outproj_kernel<<<dim3(32, 8), 256, 0, stream>>>(ctxb, wob, bo, out);
}

// Round 16
// 148.009 us; speedup vs baseline: 1.0307x; 1.0022x over previous
//
#include <hip/hip_runtime.h>
#include <hip/hip_bf16.h>
#include <math.h>

#define S 4096
#define D 512
#define H 8
#define DK 64
#define WIN 128

typedef __attribute__((ext_vector_type(8))) short bf16x8;
typedef __attribute__((ext_vector_type(4))) float f32x4;

__device__ __forceinline__ unsigned short f2bf(float f) {
    __hip_bfloat16 h = __float2bfloat16(f);
    return *(unsigned short*)&h;
}

// ---------------------------------------------------------------------------
// fp32 -> bf16: x (y=0) and the 4 weight matrices (y=1..4). 8 elems/thread.
// ---------------------------------------------------------------------------
__global__ __launch_bounds__(256) void conv_bf16_kernel(
    const float* __restrict__ x,
    const float* __restrict__ wq, const float* __restrict__ wk,
    const float* __restrict__ wv, const float* __restrict__ wo,
    unsigned short* __restrict__ xb,
    unsigned short* __restrict__ wqb, unsigned short* __restrict__ wkb,
    unsigned short* __restrict__ wvb, unsigned short* __restrict__ wob)
{
    const float* src; unsigned short* dst; int n;
    switch (blockIdx.y) {
        case 0:  src = x;  dst = xb;  n = S * D; break;
        case 1:  src = wq; dst = wqb; n = D * D; break;
        case 2:  src = wk; dst = wkb; n = D * D; break;
        case 3:  src = wv; dst = wvb; n = D * D; break;
        default: src = wo; dst = wob; n = D * D; break;
    }
    const int i = (blockIdx.x * 256 + threadIdx.x) * 8;
    if (i >= n) return;
    float4 a = *(const float4*)&src[i];
    float4 b = *(const float4*)&src[i + 4];
    ushort4 o0 = {f2bf(a.x), f2bf(a.y), f2bf(a.z), f2bf(a.w)};
    ushort4 o1 = {f2bf(b.x), f2bf(b.y), f2bf(b.z), f2bf(b.w)};
    *(ushort4*)&dst[i]     = o0;
    *(ushort4*)&dst[i + 4] = o1;
}

// ---------------------------------------------------------------------------
// MFMA GEMM: C[m][n] = sum_e A[m][e]*W16[n][e] + bias[n]
// BK-split staging: two 256-wide B halves, Bs = 33.8 KB -> 4 blocks/CU.
// Outputs: C (fp32) and/or CB (bf16 row-major) and/or CBT (bf16 transposed,
// CBT[col*4096 + row] — used to emit vT directly from the V projection).
// ---------------------------------------------------------------------------
__device__ __forceinline__ void mfma_gemm_body(
    const unsigned short* __restrict__ A,
    const unsigned short* __restrict__ W16,
    const float* __restrict__ bias,
    float* __restrict__ C,
    unsigned short* __restrict__ CB,
    unsigned short* __restrict__ CBT)
{
    __shared__ unsigned short Bs[64][264];   // 33.8 KB

    const int tid  = threadIdx.x;
    const int m0   = blockIdx.x * 128;
    const int n0   = blockIdx.y * 64;
    const int wv   = tid >> 6;
    const int lane = tid & 63;
    const int l16  = lane & 15;
    const int klo  = (lane >> 4) * 8;

    const unsigned short* arow0 = &A[(size_t)(m0 + wv * 32 + l16) * 512 + klo];
    const unsigned short* arow1 = arow0 + 16 * 512;

    f32x4 acc[2][4];
    #pragma unroll
    for (int r = 0; r < 2; ++r)
        #pragma unroll
        for (int nf = 0; nf < 4; ++nf)
            acc[r][nf] = (f32x4){0.f, 0.f, 0.f, 0.f};

    #pragma unroll
    for (int half = 0; half < 2; ++half) {
        const int kbase = half * 256;
        // stage 64 rows x 256 cols bf16 = 32 KB; 8 x bf16x8 per thread
        #pragma unroll
        for (int it = 0; it < 8; ++it) {
            const int c   = tid + it * 256;
            const int row = c >> 5;
            const int kc  = (c & 31) * 8;
            *(bf16x8*)&Bs[row][kc] =
                *(const bf16x8*)&W16[(size_t)(n0 + row) * 512 + kbase + kc];
        }
        __syncthreads();

        #pragma unroll 4
        for (int kb = 0; kb < 256; kb += 32) {
            bf16x8 a0 = *(const bf16x8*)&arow0[kbase + kb];
            bf16x8 a1 = *(const bf16x8*)&arow1[kbase + kb];
            #pragma unroll
            for (int nf = 0; nf < 4; ++nf) {
                bf16x8 b = *(const bf16x8*)&Bs[nf * 16 + l16][kb + klo];
                acc[0][nf] = __builtin_amdgcn_mfma_f32_16x16x32_bf16(a0, b, acc[0][nf], 0, 0, 0);
                acc[1][nf] = __builtin_amdgcn_mfma_f32_16x16x32_bf16(a1, b, acc[1][nf], 0, 0, 0);
            }
        }
        __syncthreads();
    }

    const int r0 = (lane >> 4) * 4;
    #pragma unroll
    for (int r = 0; r < 2; ++r) {
        #pragma unroll
        for (int nf = 0; nf < 4; ++nf) {
            const int col = n0 + nf * 16 + l16;
            const float bb = bias[col];
            if (CBT) {
                // transposed bf16 write: 4 consecutive rows -> ushort4
                ushort4 o;
                o.x = f2bf(acc[r][nf][0] + bb);
                o.y = f2bf(acc[r][nf][1] + bb);
                o.z = f2bf(acc[r][nf][2] + bb);
                o.w = f2bf(acc[r][nf][3] + bb);
                const int row0 = m0 + wv * 32 + r * 16 + r0;
                *(ushort4*)&CBT[(size_t)col * 4096 + row0] = o;
            } else {
                #pragma unroll
                for (int vv = 0; vv < 4; ++vv) {
                    const int row = m0 + wv * 32 + r * 16 + r0 + vv;
                    const float val = acc[r][nf][vv] + bb;
                    if (C)  C [(size_t)row * 512 + col] = val;
                    if (CB) CB[(size_t)row * 512 + col] = f2bf(val);
                }
            }
        }
    }
}

__global__ __launch_bounds__(256) void proj3_kernel(
    const unsigned short* __restrict__ xb,
    const unsigned short* __restrict__ wqb, const float* __restrict__ bq,
    const unsigned short* __restrict__ wkb, const float* __restrict__ bk,
    const unsigned short* __restrict__ wvb, const float* __restrict__ bv,
    unsigned short* __restrict__ qb, unsigned short* __restrict__ kb,
    unsigned short* __restrict__ vT)
{
    if (blockIdx.z == 0)
        mfma_gemm_body(xb, wqb, bq, nullptr, qb, nullptr);
    else if (blockIdx.z == 1)
        mfma_gemm_body(xb, wkb, bk, nullptr, kb, nullptr);
    else
        mfma_gemm_body(xb, wvb, bv, nullptr, nullptr, vT);   // direct-transposed V
}

__global__ __launch_bounds__(256) void outproj_kernel(
    const unsigned short* __restrict__ ctxb,
    const unsigned short* __restrict__ wob, const float* __restrict__ bo,
    float* __restrict__ out)
{
    mfma_gemm_body(ctxb, wob, bo, out, nullptr, nullptr);
}

// ---------------------------------------------------------------------------
// Fused band attention (round-15, verified): MFMA QK^T (K staged to LDS,
// Q in registers) -> softmax (P zeroed out-of-band) -> MFMA PV (V staged
// from vT via vector LDS writes into the same KV buffer) -> ctx write ->
// full-row attn write. LDS ~31 KB -> 5 blocks/CU. QB=16, grid (256, 8).
// ---------------------------------------------------------------------------
__global__ __launch_bounds__(256) void band_attn_kernel(
    const unsigned short* __restrict__ qb, const unsigned short* __restrict__ kb,
    const unsigned short* __restrict__ vT,
    float* __restrict__ attn, unsigned short* __restrict__ ctxb)
{
    __shared__ __align__(16) unsigned short KV[64][72];  // K:[key][d] / V:[d][s]
    __shared__ float P[16][336];                         // exp-scores
    __shared__ float rinvs[16];

    const int tid = threadIdx.x;
    const int h  = blockIdx.y;
    const int q0 = blockIdx.x * 16;
    const int w0 = q0 - 128;

    const int wv   = tid >> 6;
    const int lane = tid & 63;
    const int l16  = lane & 15;
    const int klo  = (lane >> 4) * 8;
    const int r0   = (lane >> 4) * 4;

    // ---- Q fragments in registers (chunk-invariant), straight from global
    const unsigned short* qrow = &qb[(size_t)(q0 + l16) * 512 + h * 64 + klo];
    const bf16x8 aq0 = *(const bf16x8*)&qrow[0];
    const bf16x8 aq1 = *(const bf16x8*)&qrow[32];

    const int lr = tid >> 2;           // K stage: key 0..63
    const int ld = (tid & 3) * 16;     // K stage: 16 d's

    // ================= QK^T phase =================
    for (int ch = 0; ch < 5; ++ch) {
        const int c0 = w0 + ch * 64;
        if (c0 + 64 <= 0 || c0 >= S) continue;   // skip fully-outside chunks
        __syncthreads();
        {
            const int krow = min(max(c0 + lr, 0), S - 1);   // clamp partials
            const unsigned short* src = &kb[(size_t)krow * 512 + h * 64 + ld];
            *(bf16x8*)&KV[lr][ld]     = *(const bf16x8*)&src[0];
            *(bf16x8*)&KV[lr][ld + 8] = *(const bf16x8*)&src[8];
        }
        __syncthreads();

        f32x4 acc = (f32x4){0.f, 0.f, 0.f, 0.f};
        bf16x8 b0 = *(const bf16x8*)&KV[wv * 16 + l16][klo];
        bf16x8 b1 = *(const bf16x8*)&KV[wv * 16 + l16][32 + klo];
        acc = __builtin_amdgcn_mfma_f32_16x16x32_bf16(aq0, b0, acc, 0, 0, 0);
        acc = __builtin_amdgcn_mfma_f32_16x16x32_bf16(aq1, b1, acc, 0, 0, 0);
        #pragma unroll
        for (int vv = 0; vv < 4; ++vv)
            P[r0 + vv][ch * 64 + wv * 16 + l16] = acc[vv] * 0.125f;
    }
    __syncthreads();

    // ---- softmax: exp in band, ZERO outside band (cols [0,320)) ----
    {
        const int r   = tid >> 4;
        const int lx  = tid & 15;
        const int i   = q0 + r;
        const int lo = max(i - WIN, 0) - w0;
        const int hi = min(i + WIN, S - 1) - w0;

        float m = -1e30f;
        for (int c = lo + lx; c <= hi; c += 16) m = fmaxf(m, P[r][c]);
        m = fmaxf(m, __shfl_xor(m, 1));
        m = fmaxf(m, __shfl_xor(m, 2));
        m = fmaxf(m, __shfl_xor(m, 4));
        m = fmaxf(m, __shfl_xor(m, 8));

        float sum = 0.f;
        for (int c = lx; c < 320; c += 16) {
            float e = 0.f;
            if (c >= lo && c <= hi) {
                e = __expf(P[r][c] - m);
                sum += e;
            }
            P[r][c] = e;
        }
        sum += __shfl_xor(sum, 1);
        sum += __shfl_xor(sum, 2);
        sum += __shfl_xor(sum, 4);
        sum += __shfl_xor(sum, 8);
        if (lx == 0) rinvs[r] = 1.0f / sum;
    }

    // ================= PV phase: V staged from vT (vector LDS writes) ======
    f32x4 pacc = (f32x4){0.f, 0.f, 0.f, 0.f};
    const int dd = tid >> 2;           // V stage: d 0..63
    const int sc = (tid & 3) * 16;     // V stage: 16 s's
    const unsigned short* vtd = &vT[((size_t)h * 64 + dd) * 4096];
    for (int ch = 0; ch < 5; ++ch) {
        const int c0 = w0 + ch * 64;
        if (c0 + 64 <= 0 || c0 >= S) continue;
        __syncthreads();
        {
            const int offs = min(max(c0 + sc, 0), S - 16);  // 16-aligned clamp; P=0 there
            *(bf16x8*)&KV[dd][sc]     = *(const bf16x8*)&vtd[offs];
            *(bf16x8*)&KV[dd][sc + 8] = *(const bf16x8*)&vtd[offs + 8];
        }
        __syncthreads();

        #pragma unroll
        for (int kk = 0; kk < 64; kk += 32) {
            f32x4 p0 = *(const f32x4*)&P[l16][ch * 64 + kk + klo];
            f32x4 p1 = *(const f32x4*)&P[l16][ch * 64 + kk + klo + 4];
            unsigned short ab[8] = {f2bf(p0[0]), f2bf(p0[1]), f2bf(p0[2]), f2bf(p0[3]),
                                    f2bf(p1[0]), f2bf(p1[1]), f2bf(p1[2]), f2bf(p1[3])};
            bf16x8 a = *(const bf16x8*)ab;
            bf16x8 b = *(const bf16x8*)&KV[wv * 16 + l16][kk + klo];
            pacc = __builtin_amdgcn_mfma_f32_16x16x32_bf16(a, b, pacc, 0, 0, 0);
        }
    }

    // ---- ctx write ----
    #pragma unroll
    for (int vv = 0; vv < 4; ++vv) {
        const int row = q0 + r0 + vv;
        ctxb[(size_t)row * 512 + h * 64 + wv * 16 + l16] =
            f2bf(pacc[vv] * rinvs[r0 + vv]);
    }

    // ---- write full attn rows, coalesced; zeros outside band ----
    float* rowbase = attn + (size_t)h * S * S;
    #pragma unroll 1
    for (int r = 0; r < 16; ++r) {
        const int i = q0 + r;
        float* rowp = rowbase + (size_t)i * S;
        const int lo = max(i - WIN, 0) - w0;
        const int hi = min(i + WIN, S - 1) - w0;
        const float rv = rinvs[r];
        #pragma unroll
        for (int t = 0; t < 4; ++t) {
            const int c4 = (tid + t * 256) << 2;
            const int lc = c4 - w0;
            float4 o;
            if (lc >= lo && lc + 3 <= hi) {
                float4 p = *(const float4*)&P[r][lc];
                o.x = p.x * rv; o.y = p.y * rv; o.z = p.z * rv; o.w = p.w * rv;
            } else if (lc + 3 < lo || lc > hi) {
                o = make_float4(0.f, 0.f, 0.f, 0.f);
            } else {
                o.x = (lc + 0 >= lo && lc + 0 <= hi) ? P[r][lc + 0] * rv : 0.f;
                o.y = (lc + 1 >= lo && lc + 1 <= hi) ? P[r][lc + 1] * rv : 0.f;
                o.z = (lc + 2 >= lo && lc + 2 <= hi) ? P[r][lc + 2] * rv : 0.f;
                o.w = (lc + 3 >= lo && lc + 3 <= hi) ? P[r][lc + 3] * rv : 0.f;
            }
            *(float4*)&rowp[c4] = o;
        }
    }
}

// ---------------------------------------------------------------------------
extern "C" void kernel_launch(void* const* d_in, const int* in_sizes, int n_in,
                              void* d_out, int out_size, void* d_ws, size_t ws_size,
                              hipStream_t stream)
{
    (void)in_sizes; (void)n_in; (void)out_size; (void)ws_size;
    const float* x  = (const float*)d_in[0];
    const float* wq = (const float*)d_in[1];
    const float* bq = (const float*)d_in[2];
    const float* wk = (const float*)d_in[3];
    const float* bk = (const float*)d_in[4];
    const float* wv = (const float*)d_in[5];
    const float* bv = (const float*)d_in[6];
    const float* wo = (const float*)d_in[7];
    const float* bo = (const float*)d_in[8];

    float* out  = (float*)d_out;                       // (S, D)
    float* attn = out + (size_t)S * D;                 // (H, S, S)

    unsigned short* xb   = (unsigned short*)d_ws;      // 4 MB each
    unsigned short* qb   = xb   + (size_t)S * D;
    unsigned short* kb   = qb   + (size_t)S * D;
    unsigned short* ctxb = kb   + (size_t)S * D;
    unsigned short* vT   = ctxb + (size_t)S * D;       // 4 MB (512 x 4096)
    unsigned short* wqb  = vT   + (size_t)S * D;       // 512 KB each
    unsigned short* wkb  = wqb  + (size_t)D * D;
    unsigned short* wvb  = wkb  + (size_t)D * D;
    unsigned short* wob  = wvb  + (size_t)D * D;

    conv_bf16_kernel<<<dim3(1024, 5), 256, 0, stream>>>(
        x, wq, wk, wv, wo, xb, wqb, wkb, wvb, wob);
    proj3_kernel<<<dim3(32, 8, 3), 256, 0, stream>>>(
        xb, wqb, bq, wkb, bk, wvb, bv, qb, kb, vT);
    band_attn_kernel<<<dim3(256, 8), 256, 0, stream>>>(qb, kb, vT, attn, ctxb);
    outproj_kernel<<<dim3(32, 8), 256, 0, stream>>>(ctxb, wob, bo, out);
}